// Round 9
// baseline (378.741 us; speedup 1.0000x reference)
//
#include <hip/hip_runtime.h>
#include <cstdint>
#include <cstddef>

// ---------------------------------------------------------------------------
// y[b,o] = sum_{i,j<257} x1[b,i] x1[b,j] W[o, i*257+j] + bias[o],  x1=[1,x]
//   main : slices ii in [0,258) (257 real + pseudo 257=j-col 256), j in [0,256)
//   corner (256,256) + bias -> init_out kernel (exact fp32)
// Round 9: round-8 pair-step pipeline with the staging-rate bug fixed.
//   - consume 2 steps/phase AND stage 2 steps/phase (4 gload_lds per wave)
//   - ring: 8 x 16KB step slots = 4 pairs; stage pair p+3 over pair p-1
//   - per-wave counted vmcnt BEFORE s_barrier (per-wave counts -> cross-wave
//     guarantee): steady WAITVM(8); tail 8/4/0. Refill (4 VM) absorbed by
//     the conservative 8 (in-order retirement).
//   - per-slice scalars in registers; no scal LDS, no prologue barrier
//   - KSPLIT=32 uniform (ii0=8s); s==31: NII=10 (slices 248..257, k>=8 ->
//     scalar x1[256]); grid 512 = 2 rounds of 1 block/CU (128KB LDS)
// ---------------------------------------------------------------------------

typedef _Float16 half8 __attribute__((ext_vector_type(8)));
typedef float    f32x4 __attribute__((ext_vector_type(4)));

#define LD8(p) (*(const half8*)(p))
#define WAITVM(N) asm volatile("s_waitcnt vmcnt(" #N ")" ::: "memory")

__device__ __forceinline__ void gload_lds16(const void* g, void* lds) {
  __builtin_amdgcn_global_load_lds(
      (const __attribute__((address_space(1))) uint32_t*)g,
      (__attribute__((address_space(3))) uint32_t*)lds, 16, 0, 0);
}

#define MFMA(a, b, c) __builtin_amdgcn_mfma_f32_16x16x32_f16((a), (b), (c), 0, 0, 0)

// ---- stage 1: W [256][66049] f32 -> Wp fragment-ordered f16 ----------------
// Wp[((ii*8+jc)*16+f)*64 + l][e] = W[o=f*16+(l&15), j=jc*32+(l>>4)*8+e] slice ii
__global__ void conv_w_k(const float* __restrict__ W, _Float16* __restrict__ Wp) {
  int t  = blockIdx.x * 256 + threadIdx.x;  // 258*8*16*64 = 2,113,536
  int l  = t & 63;
  int f  = (t >> 6) & 15;
  int jc = (t >> 10) & 7;
  int ii = t >> 13;                          // 0..257
  int o  = f * 16 + (l & 15);
  int j0 = jc * 32 + (l >> 4) * 8;
  half8 h;
  if (ii < 257) {
    const float* src = W + (size_t)o * 66049 + (size_t)ii * 257 + j0;
#pragma unroll
    for (int e = 0; e < 8; ++e) h[e] = (_Float16)src[e];
  } else {
    const float* src = W + (size_t)o * 66049 + 256;
#pragma unroll
    for (int e = 0; e < 8; ++e) h[e] = (_Float16)src[(size_t)(j0 + e) * 257];
  }
  *(half8*)(Wp + (size_t)t * 8) = h;
}

// ---- stage 1b: x [2048][256] f32 -> X1g [2048][264] f16 (x1 padded) ---------
__global__ void conv_x1_k(const float* __restrict__ x, _Float16* __restrict__ X1g) {
  int t  = blockIdx.x * 256 + threadIdx.x;    // total 2048*33 = 67584
  int j8 = t % 33;
  int b  = t / 33;
  half8 h;
#pragma unroll
  for (int u = 0; u < 8; ++u) {
    int jj = j8 * 8 + u;
    float v = (jj == 0) ? 1.0f : (jj <= 256 ? x[(size_t)b * 256 + (jj - 1)] : 0.0f);
    h[u] = (_Float16)v;
  }
  *(half8*)(X1g + (size_t)b * 264 + j8 * 8) = h;
}

// ---- init: Y = bias + x1[256]^2 * W[o,66048]  (exact fp32 terms) ------------
__global__ void init_out_k(const float* __restrict__ x, const float* __restrict__ W,
                           const float* __restrict__ bias, float* __restrict__ Y) {
  int o = threadIdx.x;
  int b = blockIdx.x;
  float xl = x[(size_t)b * 256 + 255];
  float w  = W[(size_t)o * 66049 + 66048];
  Y[(size_t)b * 256 + o] = bias[o] + xl * xl * w;
}

// ---- pair-step core ---------------------------------------------------------
template<int NII>
__device__ __forceinline__ void core_fn(
    const char* __restrict__ gW,     // staging src (per-lane, ii0 applied)
    char* __restrict__ ldsW,         // staging dst (wave-uniform window)
    const _Float16* __restrict__ wbuf,
    const _Float16* __restrict__ xr, // x1 row ptr (+ mf*16*264 + jc*32)
    half8 s80, half8 s81, half8 s82, half8 s83,
    _Float16 s90, _Float16 s91, _Float16 s92, _Float16 s93,
    int wn, int l, f32x4 acc[4][4])
{
  constexpr int NP = NII / 2;      // pairs per jc
  half8 cur[4], curN[4];
#pragma unroll
  for (int mf = 0; mf < 4; ++mf)
    cur[mf] = LD8(xr + (size_t)(mf * 16) * 264);

  // prologue: stage steps 0..5 (pairs 0,1,2) of jc=0 into slots 0..5
#pragma unroll
  for (int k0 = 0; k0 < 6; ++k0) {
    char* d = ldsW + k0 * 16384;
    gload_lds16(gW + (size_t)k0 * 131072, d);
    gload_lds16(gW + (size_t)k0 * 131072 + 8192, d + 8192);
  }

  for (int jc = 0; jc < 8; ++jc) {
#pragma unroll
    for (int kp = 0; kp < NP; ++kp) {
      const int k  = 2 * kp;
      const int p  = jc * NP + kp;   // global pair index, 0..8*NP-1
      const int st = 2 * p;

      // per-wave counted drain, THEN barrier (cross-wave guarantee)
      if (jc < 7) { WAITVM(8); }
      else {
        if (kp <= NP - 3)      { WAITVM(8); }
        else if (kp == NP - 2) { WAITVM(4); }
        else                   { WAITVM(0); }
      }
      __builtin_amdgcn_s_barrier();

      // batched ds_read: this pair's 8 fragments (conflict-free b128)
      const _Float16* wb0 = wbuf + (size_t)((st    ) & 7) * 8192 + wn * 2048 + l * 8;
      const _Float16* wb1 = wbuf + (size_t)((st + 1) & 7) * 8192 + wn * 2048 + l * 8;
      half8 a0 = LD8(wb0), a1 = LD8(wb0 + 512), a2 = LD8(wb0 + 1024), a3 = LD8(wb0 + 1536);
      half8 b0 = LD8(wb1), b1 = LD8(wb1 + 512), b2 = LD8(wb1 + 1024), b3 = LD8(wb1 + 1536);

      // cur refill one jc ahead (4 VM instrs, absorbed by WAITVM(8) margin)
      if (kp == NP - 2 && jc < 7) {
#pragma unroll
        for (int mf = 0; mf < 4; ++mf)
          curN[mf] = LD8(xr + (size_t)(mf * 16) * 264 + (jc + 1) * 32);
      }

      // stage FULL pair p+3 (steps 2(p+3), 2(p+3)+1): 4 gload_lds
      if (p + 3 <= 8 * NP - 1) {
        const int pt  = p + 3;
        const int jct = pt / NP;
        const int ktp = pt - jct * NP;
        const size_t boff = (size_t)(ktp * 16 + jct) * 16384;  // (2ktp*8+jct)*16KB
        const int sl = (2 * pt) & 7;                            // even slot
        char* d0 = ldsW + sl * 16384;
        gload_lds16(gW + boff, d0);
        gload_lds16(gW + boff + 8192, d0 + 8192);
        char* d1 = d0 + 16384;                                  // slot sl+1 (<=7)
        gload_lds16(gW + boff + 131072, d1);                    // step k+1 block
        gload_lds16(gW + boff + 131072 + 8192, d1 + 8192);
      }

      __builtin_amdgcn_s_setprio(1);
#pragma unroll
      for (int mf = 0; mf < 4; ++mf) {
        _Float16 e = (k < 8)
            ? ((mf == 0) ? s80[k] : (mf == 1) ? s81[k] : (mf == 2) ? s82[k] : s83[k])
            : ((mf == 0) ? s90 : (mf == 1) ? s91 : (mf == 2) ? s92 : s93);
        half8 v = {e, e, e, e, e, e, e, e};
        half8 af = cur[mf] * v;                      // v_pk_mul_f16
        acc[mf][0] = MFMA(af, a0, acc[mf][0]);
        acc[mf][1] = MFMA(af, a1, acc[mf][1]);
        acc[mf][2] = MFMA(af, a2, acc[mf][2]);
        acc[mf][3] = MFMA(af, a3, acc[mf][3]);
      }
#pragma unroll
      for (int mf = 0; mf < 4; ++mf) {
        const int k1 = k + 1;
        _Float16 e = (k1 < 8)
            ? ((mf == 0) ? s80[k1] : (mf == 1) ? s81[k1] : (mf == 2) ? s82[k1] : s83[k1])
            : ((mf == 0) ? s90 : (mf == 1) ? s91 : (mf == 2) ? s92 : s93);
        half8 v = {e, e, e, e, e, e, e, e};
        half8 af = cur[mf] * v;
        acc[mf][0] = MFMA(af, b0, acc[mf][0]);
        acc[mf][1] = MFMA(af, b1, acc[mf][1]);
        acc[mf][2] = MFMA(af, b2, acc[mf][2]);
        acc[mf][3] = MFMA(af, b3, acc[mf][3]);
      }
      __builtin_amdgcn_s_setprio(0);
    }
    if (jc < 7) {
#pragma unroll
      for (int mf = 0; mf < 4; ++mf) cur[mf] = curN[mf];
    }
  }
}

// ---- main GEMM --------------------------------------------------------------
__global__ __launch_bounds__(512, 2)
void gemm_k(const _Float16* __restrict__ Wp, const _Float16* __restrict__ X1g,
            float* __restrict__ Y) {
  __shared__ __align__(16) _Float16 wbuf[8 * 8192];   // 128 KB: 8 step slots

  const int bid = blockIdx.x;
  const int s   = bid & 31;              // split; bid%8 == s%8 -> XCD pinned
  const int mt  = bid >> 5;              // m-tile (BM=128), 0..15
  const int ii0 = s * 8;                 // s<31: slices 8s..8s+7; s=31: ..257

  const int tid = threadIdx.x;
  const int l   = tid & 63;
  const int w   = tid >> 6;   // wave 0..7
  const int wm  = w >> 2;     // m-group 0..1
  const int wn  = w & 3;      // n-group 0..3
  const int ln  = l & 15;
  const int ks  = l >> 4;

  const int row = mt * 128 + wm * 64 + ln;
  const _Float16* xr = X1g + (size_t)row * 264 + ks * 8;

  // per-slice scalars in registers: s8x[k] = x1[row+mf*16, ii0+k], k<8
  half8 s80 = LD8(X1g + (size_t)(row +  0) * 264 + ii0);
  half8 s81 = LD8(X1g + (size_t)(row + 16) * 264 + ii0);
  half8 s82 = LD8(X1g + (size_t)(row + 32) * 264 + ii0);
  half8 s83 = LD8(X1g + (size_t)(row + 48) * 264 + ii0);
  _Float16 s90 = (_Float16)0.f, s91 = (_Float16)0.f,
           s92 = (_Float16)0.f, s93 = (_Float16)0.f;
  if (s == 31) {   // k=8 -> slice 256 (x1[256]); k=9 -> pseudo 257 (x1[256])
    s90 = X1g[(size_t)(row +  0) * 264 + 256];
    s91 = X1g[(size_t)(row + 16) * 264 + 256];
    s92 = X1g[(size_t)(row + 32) * 264 + 256];
    s93 = X1g[(size_t)(row + 48) * 264 + 256];
  }

  // W staging: per-lane global src; wave-uniform LDS dest window
  const char* gW   = (const char*)Wp + (size_t)ii0 * 131072 + w * 1024 + l * 16;
  char*       ldsW = (char*)wbuf + w * 1024;

  f32x4 acc[4][4];
#pragma unroll
  for (int mf = 0; mf < 4; ++mf)
#pragma unroll
    for (int nf = 0; nf < 4; ++nf) acc[mf][nf] = (f32x4){0.f, 0.f, 0.f, 0.f};

  if (s == 31)
    core_fn<10>(gW, ldsW, wbuf, xr, s80, s81, s82, s83, s90, s91, s92, s93, wn, l, acc);
  else
    core_fn<8>(gW, ldsW, wbuf, xr, s80, s81, s82, s83, s90, s91, s92, s93, wn, l, acc);

  // ---- epilogue: atomic accumulate (C/D: col=l&15, row=ks*4+r) ----
  float* yb = Y + (size_t)(mt * 128 + wm * 64) * 256 + wn * 64;
  const int r0 = ks * 4;
#pragma unroll
  for (int mf = 0; mf < 4; ++mf)
#pragma unroll
    for (int nf = 0; nf < 4; ++nf)
#pragma unroll
      for (int r = 0; r < 4; ++r)
        unsafeAtomicAdd(&yb[(size_t)(mf * 16 + r0 + r) * 256 + nf * 16 + ln],
                        acc[mf][nf][r]);
}

// ---- emergency fallback if ws too small (correct, slow) ---------------------
__global__ void fb_k(const float* __restrict__ x, const float* __restrict__ W,
                     const float* __restrict__ bias, float* __restrict__ Y) {
  __shared__ float x1[257];
  int b = blockIdx.x, o = threadIdx.x;
  x1[o + 1] = x[(size_t)b * 256 + o];
  if (o == 0) x1[0] = 1.0f;
  __syncthreads();
  const float* Wr = W + (size_t)o * 66049;
  float acc = bias[o];
  for (int i = 0; i < 257; ++i) {
    const float* wr = Wr + (size_t)i * 257;
    float p = 0.f;
    for (int j = 0; j < 257; ++j) p = fmaf(x1[j], wr[j], p);
    acc = fmaf(x1[i], p, acc);
  }
  Y[(size_t)b * 256 + o] = acc;
}

extern "C" void kernel_launch(void* const* d_in, const int* in_sizes, int n_in,
                              void* d_out, int out_size, void* d_ws, size_t ws_size,
                              hipStream_t stream) {
  const float* x = (const float*)d_in[0];
  const float* W = (const float*)d_in[1];
  const float* b = (const float*)d_in[2];
  float* y = (float*)d_out;

  const size_t WPB = (size_t)258 * 8 * 16 * 64 * 16;  // 33,816,576 B
  const size_t X1B = (size_t)2048 * 264 * 2;          //  1,081,344 B
  if (ws_size < WPB + X1B) {
    fb_k<<<2048, 256, 0, stream>>>(x, W, b, y);
    return;
  }
  _Float16* Wp  = (_Float16*)d_ws;
  _Float16* X1g = (_Float16*)((char*)d_ws + WPB);

  conv_w_k<<<8256, 256, 0, stream>>>(W, Wp);
  conv_x1_k<<<264, 256, 0, stream>>>(x, X1g);
  init_out_k<<<2048, 256, 0, stream>>>(x, W, b, y);
  gemm_k<<<512, 512, 0, stream>>>(Wp, X1g, y);
}